// Round 1
// baseline (652.155 us; speedup 1.0000x reference)
//
#include <hip/hip_runtime.h>
#include <math.h>

#define HID 256
#define NBINS 4
#define NMIR 2000
#define NMRNA 20000
#define NG (NMRNA + NMIR)   // 22000 union gene space
#define BB 16
#define NP 2048
#define PD 1024
#define EREG 300000
#define EPM 320000
#define EPI 32000

typedef __attribute__((ext_vector_type(8))) short bf16x8;
typedef __attribute__((ext_vector_type(4))) float f32x4;

__device__ __forceinline__ float gelu_exact(float x) {
    return 0.5f * x * (1.0f + erff(x * 0.7071067811865475f));
}

// fp32 -> bf16 round-to-nearest-even (bits)
__device__ __forceinline__ unsigned short f2b(float f) {
    union { float f; unsigned int u; } v; v.f = f;
    unsigned int u = v.u + 0x7fffu + ((v.u >> 16) & 1u);
    return (unsigned short)(u >> 16);
}

// blockDim.x == 1024 assumed
__device__ __forceinline__ float block_reduce_sum_1024(float v, float* red) {
    int t = threadIdx.x;
    red[t] = v;
    __syncthreads();
    for (int st = 512; st > 0; st >>= 1) {
        if (t < st) red[t] += red[t + st];
        __syncthreads();
    }
    float r = red[0];
    __syncthreads();
    return r;
}

// 4 independent 256-wide reductions (one per r-group); result broadcast within group
__device__ __forceinline__ float group_reduce_sum_256(float v, float* red, int c, int r) {
    red[(r << 8) + c] = v;
    __syncthreads();
    for (int st = 128; st > 0; st >>= 1) {
        if (c < st) red[(r << 8) + c] += red[(r << 8) + c + st];
        __syncthreads();
    }
    float out = red[r << 8];
    __syncthreads();
    return out;
}

// ---------- both reg weights fp32 -> bf16, one launch ----------
__global__ void k_f2b_w(const float* __restrict__ wA, const float* __restrict__ wB,
                        unsigned short* __restrict__ out) {
    int i = blockIdx.x * blockDim.x + threadIdx.x;
    if (i < HID * HID) out[i] = f2b(wA[i]);
    else if (i < 2 * HID * HID) out[i] = f2b(wB[i - HID * HID]);
}

// ---------- CSR histogram, both etypes into contiguous cnt[NG] ----------
__global__ void k_hist2(const int* __restrict__ dA, const int* __restrict__ dB,
                        int* __restrict__ cnt) {
    int i = blockIdx.x * blockDim.x + threadIdx.x;
    if (i < EREG) atomicAdd(&cnt[dA[i]], 1);
    else if (i < 2 * EREG) atomicAdd(&cnt[NMRNA + dB[i - EREG]], 1);
}

// ---------- exclusive scan: block 0 -> mrna CSR, block 1 -> mir CSR ----------
__global__ __launch_bounds__(1024) void k_scan2(const int* __restrict__ cnt,
                                                int* __restrict__ rpA, int* __restrict__ cuA,
                                                int* __restrict__ rpB, int* __restrict__ cuB) {
    __shared__ int part[1024];
    const int* c = (blockIdx.x == 0) ? cnt : cnt + NMRNA;
    int n = (blockIdx.x == 0) ? NMRNA : NMIR;
    int* rowptr = (blockIdx.x == 0) ? rpA : rpB;
    int* cursor = (blockIdx.x == 0) ? cuA : cuB;
    int t = threadIdx.x;
    int chunk = (n + 1023) >> 10;
    int beg = t * chunk;
    int end = min(beg + chunk, n);
    int s = 0;
    for (int i = beg; i < end; i++) s += c[i];
    part[t] = s;
    __syncthreads();
    for (int st = 1; st < 1024; st <<= 1) {
        int v = (t >= st) ? part[t - st] : 0;
        __syncthreads();
        part[t] += v;
        __syncthreads();
    }
    int off = part[t] - s;  // exclusive prefix
    for (int i = beg; i < end; i++) {
        rowptr[i] = off;
        cursor[i] = off;
        off += c[i];
    }
    if (end == n) rowptr[n] = off;
}

// ---------- placement: permute (src, w) into CSR order (no eidx indirection) ----------
__global__ void k_place2(
        const int* __restrict__ srcA, const int* __restrict__ dstA, const float* __restrict__ wA,
        int* __restrict__ cuA, int* __restrict__ srcpA, float* __restrict__ wpA,
        const int* __restrict__ srcB, const int* __restrict__ dstB, const float* __restrict__ wB,
        int* __restrict__ cuB, int* __restrict__ srcpB, float* __restrict__ wpB) {
    int i = blockIdx.x * blockDim.x + threadIdx.x;
    if (i < EREG) {
        int p = atomicAdd(&cuA[dstA[i]], 1);
        srcpA[p] = srcA[i];
        wpA[p] = wA[i];
    } else if (i < 2 * EREG) {
        int j = i - EREG;
        int p = atomicAdd(&cuB[dstB[j]], 1);
        srcpB[p] = srcB[j];
        wpB[p] = wB[j];
    }
}

// ---------- CSR gather, both etypes: one block per dst node; bf16 out [NG][256] ----------
__global__ __launch_bounds__(256) void k_gather2(
        const float* __restrict__ emb_mirna, const float* __restrict__ emb_mrna,
        const int* __restrict__ rpA, const int* __restrict__ srcpA, const float* __restrict__ wpA,
        const int* __restrict__ rpB, const int* __restrict__ srcpB, const float* __restrict__ wpB,
        unsigned short* __restrict__ agg) {
    __shared__ float lacc[4][HID];
    int n = blockIdx.x;
    const float* emb;
    const int* rp; const int* srcp; const float* wp;
    int node;
    if (n < NMRNA) { emb = emb_mirna; rp = rpA; srcp = srcpA; wp = wpA; node = n; }
    else           { emb = emb_mrna;  rp = rpB; srcp = srcpB; wp = wpB; node = n - NMRNA; }
    int wv = threadIdx.x >> 6, lane = threadIdx.x & 63;
    int beg = rp[node], end = rp[node + 1];
    float a0 = 0.f, a1 = 0.f, a2 = 0.f, a3 = 0.f;
    for (int j = beg + wv; j < end; j += 4) {
        int s = srcp[j];          // wave-uniform -> s_load
        float we = wp[j];
        const float* hp = emb + (size_t)s * HID;
        a0 += we * hp[lane];
        a1 += we * hp[lane + 64];
        a2 += we * hp[lane + 128];
        a3 += we * hp[lane + 192];
    }
    lacc[wv][lane] = a0;
    lacc[wv][lane + 64] = a1;
    lacc[wv][lane + 128] = a2;
    lacc[wv][lane + 192] = a3;
    __syncthreads();
    int c = threadIdx.x;
    agg[(size_t)n * HID + c] = f2b(lacc[0][c] + lacc[1][c] + lacc[2][c] + lacc[3][c]);
}

// ---------- MFMA node update, both etypes: h = emb + gelu(A @ W^T + bias) ----------
// A: [NG][256] bf16. wb: [2][256][256] bf16 in ORIGINAL [out][in] layout (B-fragment-ready).
// Block = 16 rows x 256 cols; wave wv covers cols [wv*64, wv*64+64) as 4 16-col tiles.
__global__ __launch_bounds__(256) void k_update2(
        const unsigned short* __restrict__ A,
        const float* __restrict__ emb_mrna, const float* __restrict__ emb_mirna,
        const unsigned short* __restrict__ wb,
        const float* __restrict__ bias_mrna, const float* __restrict__ bias_mirna,
        float* __restrict__ h) {
    int row0 = blockIdx.x * 16;   // global row (NG space); NMRNA % 16 == 0, never straddles
    const float* emb; const unsigned short* Wb; const float* bias; int base;
    if (row0 < NMRNA) { emb = emb_mrna;  Wb = wb;             bias = bias_mrna;  base = 0; }
    else              { emb = emb_mirna; Wb = wb + HID * HID; bias = bias_mirna; base = NMRNA; }
    int wv = threadIdx.x >> 6;
    int lane = threadIdx.x & 63;
    int m = lane & 15;   // A row offset / D col offset
    int q = lane >> 4;   // quad: k = q*8 + j
    bf16x8 afrag[8];
    const unsigned short* arow = A + (size_t)(row0 + m) * HID + q * 8;
#pragma unroll
    for (int kk = 0; kk < 8; kk++)
        afrag[kk] = *(const bf16x8*)(arow + kk * 32);
    f32x4 acc[4];
#pragma unroll
    for (int t = 0; t < 4; t++) acc[t] = (f32x4){0.f, 0.f, 0.f, 0.f};
    int col_base = wv * 64;
#pragma unroll
    for (int t = 0; t < 4; t++) {
        const unsigned short* brow = Wb + (size_t)(col_base + t * 16 + m) * HID + q * 8;
#pragma unroll
        for (int kk = 0; kk < 8; kk++) {
            bf16x8 bfrag = *(const bf16x8*)(brow + kk * 32);
            acc[t] = __builtin_amdgcn_mfma_f32_16x16x32_bf16(afrag[kk], bfrag, acc[t], 0, 0, 0);
        }
    }
#pragma unroll
    for (int t = 0; t < 4; t++) {
        int col = col_base + t * 16 + m;
        float bv = bias[col];
#pragma unroll
        for (int r = 0; r < 4; r++) {
            int row = row0 + q * 4 + r;                      // global
            size_t idxh = (size_t)row * HID + col;
            size_t idxe = (size_t)(row - base) * HID + col;  // local emb row
            h[idxh] = emb[idxe] + gelu_exact(acc[t][r] + bv);
        }
    }
}

// ---------- pat readout weights, both etypes: Wp[b][g] += w (g in NG union space) ----------
__global__ void k_wscatter2(
        const int* __restrict__ srcA, const int* __restrict__ dstA, const float* __restrict__ wA,
        const int* __restrict__ srcB, const int* __restrict__ dstB, const float* __restrict__ wB,
        float* __restrict__ Wp) {
    int i = blockIdx.x * blockDim.x + threadIdx.x;
    if (i < EPM) {
        atomicAdd(&Wp[(size_t)dstA[i] * NG + srcA[i]], wA[i]);
    } else if (i < EPM + EPI) {
        int j = i - EPM;
        atomicAdd(&Wp[(size_t)dstB[j] * NG + NMRNA + srcB[j]], wB[j]);
    }
}

// ---------- acc_pat[b][c] += sum_g Wp[b][g] * h[g][c]  (skinny dense matmul) ----------
#define GCH 128
__global__ __launch_bounds__(256) void k_pat_dense(
        const float* __restrict__ Wp, const float* __restrict__ h,
        float* __restrict__ acc_pat) {
    int c = threadIdx.x;
    int g0 = blockIdx.x * GCH;
    int gend = min(g0 + GCH, NG);
    float acc[BB];
#pragma unroll
    for (int b = 0; b < BB; b++) acc[b] = 0.f;
    for (int g = g0; g < gend; g++) {
        float hv = h[(size_t)g * HID + c];  // coalesced
#pragma unroll
        for (int b = 0; b < BB; b++) acc[b] += Wp[(size_t)b * NG + g] * hv;  // uniform
    }
#pragma unroll
    for (int b = 0; b < BB; b++) atomicAdd(&acc_pat[b * HID + c], acc[b]);
}

// ---------- masked patch pooling (raw sums, no denom) ----------
#define PSLICES 32
#define PCHUNK (NP / PSLICES)
__global__ __launch_bounds__(256) void k_pool(
        const float* __restrict__ patches, const float* __restrict__ mask,
        float* __restrict__ pooled) {
    int b = blockIdx.y;
    int p0 = blockIdx.x * PCHUNK;
    int t = threadIdx.x;  // 256 threads x float4 = 1024 = PD
    float4 acc = {0.f, 0.f, 0.f, 0.f};
    for (int p = p0; p < p0 + PCHUNK; p++) {
        float m = mask[b * NP + p];  // uniform -> s_load
        float4 v = ((const float4*)(patches + ((size_t)b * NP + p) * PD))[t];
        acc.x += m * v.x; acc.y += m * v.y; acc.z += m * v.z; acc.w += m * v.w;
    }
    float* op = pooled + (size_t)b * PD + t * 4;
    atomicAdd(op + 0, acc.x);
    atomicAdd(op + 1, acc.y);
    atomicAdd(op + 2, acc.z);
    atomicAdd(op + 3, acc.w);
}

// ---------- fused heads: one block per patient b; 1024 threads = (col c, quarter r) ----------
// Every dot product is split 4-way across r (LDS partial combine); the NBINS=4 output
// reductions map o <- r and run as ONE segmented reduce instead of 4 serial ones.
__global__ __launch_bounds__(1024) void k_head(
        const float* __restrict__ pooled, const float* __restrict__ mask,
        const float* __restrict__ acc_pat,
        const float* __restrict__ proj_w, const float* __restrict__ proj_b,
        const float* __restrict__ ln_g, const float* __restrict__ ln_b,
        const float* __restrict__ omics_w, const float* __restrict__ omics_b,
        const float* __restrict__ wsi_w, const float* __restrict__ wsi_b,
        const float* __restrict__ mlp_w, const float* __restrict__ mlp_b,
        const float* __restrict__ wln_g, const float* __restrict__ wln_b,
        const float* __restrict__ fuse_w1, const float* __restrict__ fuse_b1,
        const float* __restrict__ fuse_w2, const float* __restrict__ fuse_b2,
        float* __restrict__ out_fused, float* __restrict__ out_omics) {
    __shared__ float red[1024];
    __shared__ float part[4][HID];
    __shared__ float vec[2 * HID];   // cat = [pat | wsi]
    __shared__ float tmp[HID];
    int b = blockIdx.x;
    int t = threadIdx.x;
    int c = t & 255;   // output column
    int r = t >> 8;    // dot-product quarter / output bin

    // ---- pat path: proj -> gelu -> LN -> vec[0:256); omics logits ----
    const float* ap = acc_pat + (size_t)b * HID;
    float t0 = 0.f;
    for (int i = r * 64; i < r * 64 + 64; i += 4) {
        float4 w4 = *(const float4*)(proj_w + (size_t)c * HID + i);
        float4 x4 = *(const float4*)(ap + i);
        t0 += x4.x * w4.x + x4.y * w4.y + x4.z * w4.z + x4.w * w4.w;
    }
    part[r][c] = t0;
    __syncthreads();
    float g = gelu_exact(part[0][c] + part[1][c] + part[2][c] + part[3][c] + proj_b[c]);
    // each c replicated 4x across r -> divide by 4*HID
    float mean = block_reduce_sum_1024(g, red) * (1.0f / (4 * HID));
    float d = g - mean;
    float var = block_reduce_sum_1024(d * d, red) * (1.0f / (4 * HID));
    float patv = d * rsqrtf(var + 1e-5f) * ln_g[c] + ln_b[c];
    if (r == 0) vec[c] = patv;
    // omics: output bin o = r, one segmented reduction for all 4 bins
    float ov = group_reduce_sum_256(patv * omics_w[r * HID + c], red, c, r);
    if (c == 0) out_omics[b * NBINS + r] = ov + omics_b[r];

    // ---- wsi path: masksum, lin1/denom, gelu, mlp, gelu, LN -> vec[256:512) ----
    float s = 0.f;
    for (int p = t; p < NP; p += 1024) s += mask[b * NP + p];
    float summask = block_reduce_sum_1024(s, red);
    float denom = fmaxf(summask, 1.0f);
    const float* pr = pooled + (size_t)b * PD;
    float t1 = 0.f;
    for (int i = r * 256; i < r * 256 + 256; i += 4) {
        float4 w4 = *(const float4*)(wsi_w + (size_t)c * PD + i);
        float4 x4 = *(const float4*)(pr + i);
        t1 += x4.x * w4.x + x4.y * w4.y + x4.z * w4.z + x4.w * w4.w;
    }
    part[r][c] = t1;
    __syncthreads();
    float po = (part[0][c] + part[1][c] + part[2][c] + part[3][c]) / denom
             + wsi_b[c] * (summask / denom);
    if (r == 0) tmp[c] = gelu_exact(po);
    __syncthreads();
    float t2 = 0.f;
    for (int i = r * 64; i < r * 64 + 64; i += 4) {
        float4 w4 = *(const float4*)(mlp_w + (size_t)c * HID + i);
        float4 x4 = *(const float4*)(tmp + i);
        t2 += x4.x * w4.x + x4.y * w4.y + x4.z * w4.z + x4.w * w4.w;
    }
    part[r][c] = t2;
    __syncthreads();
    float m = gelu_exact(part[0][c] + part[1][c] + part[2][c] + part[3][c] + mlp_b[c]);
    mean = block_reduce_sum_1024(m, red) * (1.0f / (4 * HID));
    d = m - mean;
    var = block_reduce_sum_1024(d * d, red) * (1.0f / (4 * HID));
    if (r == 0) vec[HID + c] = d * rsqrtf(var + 1e-5f) * wln_g[c] + wln_b[c];
    __syncthreads();

    // ---- fusion: gelu(cat @ fuse_w1^T + b1) @ fuse_w2^T + b2 ----
    float t3 = 0.f;
    for (int i = r * 128; i < r * 128 + 128; i += 4) {
        float4 w4 = *(const float4*)(fuse_w1 + (size_t)c * (2 * HID) + i);
        float4 x4 = *(const float4*)(vec + i);
        t3 += x4.x * w4.x + x4.y * w4.y + x4.z * w4.z + x4.w * w4.w;
    }
    part[r][c] = t3;
    __syncthreads();
    float h1 = gelu_exact(part[0][c] + part[1][c] + part[2][c] + part[3][c] + fuse_b1[c]);
    float fv = group_reduce_sum_256(h1 * fuse_w2[r * HID + c], red, c, r);
    if (c == 0) out_fused[b * NBINS + r] = fv + fuse_b2[r];
}

extern "C" void kernel_launch(void* const* d_in, const int* in_sizes, int n_in,
                              void* d_out, int out_size, void* d_ws, size_t ws_size,
                              hipStream_t stream) {
    const float* emb_mirna  = (const float*)d_in[0];
    const float* emb_mrna   = (const float*)d_in[1];
    const float* w_mir2mrna = (const float*)d_in[2];
    const float* w_mrna2mir = (const float*)d_in[3];
    const float* w_mrna2pat = (const float*)d_in[4];
    const float* w_mir2pat  = (const float*)d_in[5];
    const float* reg_w_mrna = (const float*)d_in[6];
    const float* reg_b_mrna = (const float*)d_in[7];
    const float* reg_w_mirna= (const float*)d_in[8];
    const float* reg_b_mirna= (const float*)d_in[9];
    const float* proj_w     = (const float*)d_in[10];
    const float* proj_b     = (const float*)d_in[11];
    const float* ln_g       = (const float*)d_in[12];
    const float* ln_b       = (const float*)d_in[13];
    const float* omics_w    = (const float*)d_in[14];
    const float* omics_b    = (const float*)d_in[15];
    const float* wsi_w      = (const float*)d_in[16];
    const float* wsi_b      = (const float*)d_in[17];
    const float* mlp_w      = (const float*)d_in[18];
    const float* mlp_b      = (const float*)d_in[19];
    const float* wln_g      = (const float*)d_in[20];
    const float* wln_b      = (const float*)d_in[21];
    const float* fuse_w1    = (const float*)d_in[22];
    const float* fuse_b1    = (const float*)d_in[23];
    const float* fuse_w2    = (const float*)d_in[24];
    const float* fuse_b2    = (const float*)d_in[25];
    const float* patches    = (const float*)d_in[26];
    const float* mask       = (const float*)d_in[27];
    const int* src_m2M = (const int*)d_in[28];
    const int* dst_m2M = (const int*)d_in[29];
    const int* src_M2m = (const int*)d_in[30];
    const int* dst_M2m = (const int*)d_in[31];
    const int* src_M2p = (const int*)d_in[32];
    const int* dst_M2p = (const int*)d_in[33];
    const int* src_m2p = (const int*)d_in[34];
    const int* dst_m2p = (const int*)d_in[35];

    float* ws = (float*)d_ws;
    // ---- zeroed region ----
    size_t off = 0;
    float* acc_pat  = ws + off; off += (size_t)BB * HID;       // 4096
    float* pooled   = ws + off; off += (size_t)BB * PD;        // 16384
    float* Wp       = ws + off; off += (size_t)BB * NG;        // [16][22000]
    int* cnt        = (int*)(ws + off); off += NG;             // [22000]
    size_t zero_floats = off;
    // ---- non-zeroed region (16B-aligned: zero_floats % 4 == 0) ----
    unsigned short* agg_bf = (unsigned short*)(ws + off); off += (size_t)NG * HID / 2;
    unsigned short* wb     = (unsigned short*)(ws + off); off += (size_t)2 * HID * HID / 2;
    float* h        = ws + off; off += (size_t)NG * HID;       // [22000][256]
    int* rowptr_A   = (int*)(ws + off); off += NMRNA + 1;
    int* cursor_A   = (int*)(ws + off); off += NMRNA;
    int* rowptr_B   = (int*)(ws + off); off += NMIR + 1;
    int* cursor_B   = (int*)(ws + off); off += NMIR;
    int* srcp_A     = (int*)(ws + off); off += EREG;
    float* wp_A     = ws + off; off += EREG;
    int* srcp_B     = (int*)(ws + off); off += EREG;
    float* wp_B     = ws + off; off += EREG;

    float* out_fused = (float*)d_out;               // [16,4]
    float* out_omics = (float*)d_out + BB * NBINS;  // [16,4]

    hipMemsetAsync(d_ws, 0, zero_floats * sizeof(float), stream);

    // 1. both reg weights -> bf16 (no transpose: [out][in] == MFMA B-fragment layout)
    k_f2b_w<<<(2 * HID * HID + 255) / 256, 256, 0, stream>>>(reg_w_mrna, reg_w_mirna, wb);

    // 2-4. CSR build, both etypes
    k_hist2<<<(2 * EREG + 255) / 256, 256, 0, stream>>>(dst_m2M, dst_M2m, cnt);
    k_scan2<<<2, 1024, 0, stream>>>(cnt, rowptr_A, cursor_A, rowptr_B, cursor_B);
    k_place2<<<(2 * EREG + 255) / 256, 256, 0, stream>>>(
        src_m2M, dst_m2M, w_mir2mrna, cursor_A, srcp_A, wp_A,
        src_M2m, dst_M2m, w_mrna2mir, cursor_B, srcp_B, wp_B);

    // 5. CSR gather (no atomics, no eidx indirection), bf16 agg out
    k_gather2<<<NG, 256, 0, stream>>>(emb_mirna, emb_mrna,
                                      rowptr_A, srcp_A, wp_A,
                                      rowptr_B, srcp_B, wp_B, agg_bf);

    // 6. MFMA node update, both etypes
    k_update2<<<NG / 16, 256, 0, stream>>>(agg_bf, emb_mrna, emb_mirna, wb,
                                           reg_b_mrna, reg_b_mirna, h);

    // 7-8. patient readout: dense weights + skinny matmul
    k_wscatter2<<<(EPM + EPI + 255) / 256, 256, 0, stream>>>(
        src_M2p, dst_M2p, w_mrna2pat, src_m2p, dst_m2p, w_mir2pat, Wp);
    k_pat_dense<<<(NG + GCH - 1) / GCH, 256, 0, stream>>>(Wp, h, acc_pat);

    // 9. wsi masked pooling
    k_pool<<<dim3(PSLICES, BB), 256, 0, stream>>>(patches, mask, pooled);

    // 10. all heads fused: one block per patient, 1024 threads (4-way split dots)
    k_head<<<BB, 1024, 0, stream>>>(pooled, mask, acc_pat,
                                    proj_w, proj_b, ln_g, ln_b, omics_w, omics_b,
                                    wsi_w, wsi_b, mlp_w, mlp_b, wln_g, wln_b,
                                    fuse_w1, fuse_b1, fuse_w2, fuse_b2,
                                    out_fused, out_omics);
}

// Round 2
// 599.036 us; speedup vs baseline: 1.0887x; 1.0887x over previous
//
#include <hip/hip_runtime.h>
#include <math.h>

#define HID 256
#define NBINS 4
#define NMIR 2000
#define NMRNA 20000
#define NG (NMRNA + NMIR)   // 22000 union gene space
#define BB 16
#define NP 2048
#define PD 1024
#define EREG 300000
#define EPM 320000
#define EPI 32000

typedef __attribute__((ext_vector_type(8))) short bf16x8;
typedef __attribute__((ext_vector_type(4))) float f32x4;

__device__ __forceinline__ float gelu_exact(float x) {
    return 0.5f * x * (1.0f + erff(x * 0.7071067811865475f));
}

// fp32 -> bf16 round-to-nearest-even (bits)
__device__ __forceinline__ unsigned short f2b(float f) {
    union { float f; unsigned int u; } v; v.f = f;
    unsigned int u = v.u + 0x7fffu + ((v.u >> 16) & 1u);
    return (unsigned short)(u >> 16);
}

// blockDim.x == 256 assumed
__device__ __forceinline__ float block_reduce_sum(float v, float* red) {
    int c = threadIdx.x;
    red[c] = v;
    __syncthreads();
    for (int st = 128; st > 0; st >>= 1) {
        if (c < st) red[c] += red[c + st];
        __syncthreads();
    }
    float r = red[0];
    __syncthreads();
    return r;
}

// 256-thread block laid out as (b = t&15, kk = t>>4); reduce over kk, result to all
__device__ __forceinline__ float kred(float v, float* red, int b, int kk) {
    red[kk * 16 + b] = v;
    __syncthreads();
    for (int st = 8; st >= 1; st >>= 1) {
        if (kk < st) red[kk * 16 + b] += red[(kk + st) * 16 + b];
        __syncthreads();
    }
    float r = red[b];
    __syncthreads();
    return r;
}

// ---------- both reg weights fp32 -> bf16, one launch ----------
__global__ void k_f2b_w(const float* __restrict__ wA, const float* __restrict__ wB,
                        unsigned short* __restrict__ out) {
    int i = blockIdx.x * blockDim.x + threadIdx.x;
    if (i < HID * HID) out[i] = f2b(wA[i]);
    else if (i < 2 * HID * HID) out[i] = f2b(wB[i - HID * HID]);
}

// ---------- CSR histogram, both etypes into contiguous cnt[NG] ----------
__global__ void k_hist2(const int* __restrict__ dA, const int* __restrict__ dB,
                        int* __restrict__ cnt) {
    int i = blockIdx.x * blockDim.x + threadIdx.x;
    if (i < EREG) atomicAdd(&cnt[dA[i]], 1);
    else if (i < 2 * EREG) atomicAdd(&cnt[NMRNA + dB[i - EREG]], 1);
}

// ---------- exclusive scan: block 0 -> mrna CSR, block 1 -> mir CSR ----------
__global__ __launch_bounds__(1024) void k_scan2(const int* __restrict__ cnt,
                                                int* __restrict__ rpA, int* __restrict__ cuA,
                                                int* __restrict__ rpB, int* __restrict__ cuB) {
    __shared__ int part[1024];
    const int* c = (blockIdx.x == 0) ? cnt : cnt + NMRNA;
    int n = (blockIdx.x == 0) ? NMRNA : NMIR;
    int* rowptr = (blockIdx.x == 0) ? rpA : rpB;
    int* cursor = (blockIdx.x == 0) ? cuA : cuB;
    int t = threadIdx.x;
    int chunk = (n + 1023) >> 10;
    int beg = t * chunk;
    int end = min(beg + chunk, n);
    int s = 0;
    for (int i = beg; i < end; i++) s += c[i];
    part[t] = s;
    __syncthreads();
    for (int st = 1; st < 1024; st <<= 1) {
        int v = (t >= st) ? part[t - st] : 0;
        __syncthreads();
        part[t] += v;
        __syncthreads();
    }
    int off = part[t] - s;  // exclusive prefix
    for (int i = beg; i < end; i++) {
        rowptr[i] = off;
        cursor[i] = off;
        off += c[i];
    }
    if (end == n) rowptr[n] = off;
}

// ---------- placement: permute (src, w) into CSR order (no eidx indirection) ----------
__global__ void k_place2(
        const int* __restrict__ srcA, const int* __restrict__ dstA, const float* __restrict__ wA,
        int* __restrict__ cuA, int* __restrict__ srcpA, float* __restrict__ wpA,
        const int* __restrict__ srcB, const int* __restrict__ dstB, const float* __restrict__ wB,
        int* __restrict__ cuB, int* __restrict__ srcpB, float* __restrict__ wpB) {
    int i = blockIdx.x * blockDim.x + threadIdx.x;
    if (i < EREG) {
        int p = atomicAdd(&cuA[dstA[i]], 1);
        srcpA[p] = srcA[i];
        wpA[p] = wA[i];
    } else if (i < 2 * EREG) {
        int j = i - EREG;
        int p = atomicAdd(&cuB[dstB[j]], 1);
        srcpB[p] = srcB[j];
        wpB[p] = wB[j];
    }
}

// ---------- CSR gather, both etypes: one block per dst node; bf16 out [NG][256] ----------
__global__ __launch_bounds__(256) void k_gather2(
        const float* __restrict__ emb_mirna, const float* __restrict__ emb_mrna,
        const int* __restrict__ rpA, const int* __restrict__ srcpA, const float* __restrict__ wpA,
        const int* __restrict__ rpB, const int* __restrict__ srcpB, const float* __restrict__ wpB,
        unsigned short* __restrict__ agg) {
    __shared__ float lacc[4][HID];
    int n = blockIdx.x;
    const float* emb;
    const int* rp; const int* srcp; const float* wp;
    int node;
    if (n < NMRNA) { emb = emb_mirna; rp = rpA; srcp = srcpA; wp = wpA; node = n; }
    else           { emb = emb_mrna;  rp = rpB; srcp = srcpB; wp = wpB; node = n - NMRNA; }
    int wv = threadIdx.x >> 6, lane = threadIdx.x & 63;
    int beg = rp[node], end = rp[node + 1];
    float a0 = 0.f, a1 = 0.f, a2 = 0.f, a3 = 0.f;
    for (int j = beg + wv; j < end; j += 4) {
        int s = srcp[j];          // wave-uniform -> s_load
        float we = wp[j];
        const float* hp = emb + (size_t)s * HID;
        a0 += we * hp[lane];
        a1 += we * hp[lane + 64];
        a2 += we * hp[lane + 128];
        a3 += we * hp[lane + 192];
    }
    lacc[wv][lane] = a0;
    lacc[wv][lane + 64] = a1;
    lacc[wv][lane + 128] = a2;
    lacc[wv][lane + 192] = a3;
    __syncthreads();
    int c = threadIdx.x;
    agg[(size_t)n * HID + c] = f2b(lacc[0][c] + lacc[1][c] + lacc[2][c] + lacc[3][c]);
}

// ---------- MFMA node update, both etypes: h = emb + gelu(A @ W^T + bias) ----------
// A: [NG][256] bf16. wb: [2][256][256] bf16 in ORIGINAL [out][in] layout (B-fragment-ready).
// Block = 16 rows x 256 cols; wave wv covers cols [wv*64, wv*64+64) as 4 16-col tiles.
__global__ __launch_bounds__(256) void k_update2(
        const unsigned short* __restrict__ A,
        const float* __restrict__ emb_mrna, const float* __restrict__ emb_mirna,
        const unsigned short* __restrict__ wb,
        const float* __restrict__ bias_mrna, const float* __restrict__ bias_mirna,
        float* __restrict__ h) {
    int row0 = blockIdx.x * 16;   // global row (NG space); NMRNA % 16 == 0, never straddles
    const float* emb; const unsigned short* Wb; const float* bias; int base;
    if (row0 < NMRNA) { emb = emb_mrna;  Wb = wb;             bias = bias_mrna;  base = 0; }
    else              { emb = emb_mirna; Wb = wb + HID * HID; bias = bias_mirna; base = NMRNA; }
    int wv = threadIdx.x >> 6;
    int lane = threadIdx.x & 63;
    int m = lane & 15;   // A row offset / D col offset
    int q = lane >> 4;   // quad: k = q*8 + j
    bf16x8 afrag[8];
    const unsigned short* arow = A + (size_t)(row0 + m) * HID + q * 8;
#pragma unroll
    for (int kk = 0; kk < 8; kk++)
        afrag[kk] = *(const bf16x8*)(arow + kk * 32);
    f32x4 acc[4];
#pragma unroll
    for (int t = 0; t < 4; t++) acc[t] = (f32x4){0.f, 0.f, 0.f, 0.f};
    int col_base = wv * 64;
#pragma unroll
    for (int t = 0; t < 4; t++) {
        const unsigned short* brow = Wb + (size_t)(col_base + t * 16 + m) * HID + q * 8;
#pragma unroll
        for (int kk = 0; kk < 8; kk++) {
            bf16x8 bfrag = *(const bf16x8*)(brow + kk * 32);
            acc[t] = __builtin_amdgcn_mfma_f32_16x16x32_bf16(afrag[kk], bfrag, acc[t], 0, 0, 0);
        }
    }
#pragma unroll
    for (int t = 0; t < 4; t++) {
        int col = col_base + t * 16 + m;
        float bv = bias[col];
#pragma unroll
        for (int r = 0; r < 4; r++) {
            int row = row0 + q * 4 + r;                      // global
            size_t idxh = (size_t)row * HID + col;
            size_t idxe = (size_t)(row - base) * HID + col;  // local emb row
            h[idxh] = emb[idxe] + gelu_exact(acc[t][r] + bv);
        }
    }
}

// ---------- pat readout weights, both etypes: Wp[b][g] += w (g in NG union space) ----------
__global__ void k_wscatter2(
        const int* __restrict__ srcA, const int* __restrict__ dstA, const float* __restrict__ wA,
        const int* __restrict__ srcB, const int* __restrict__ dstB, const float* __restrict__ wB,
        float* __restrict__ Wp) {
    int i = blockIdx.x * blockDim.x + threadIdx.x;
    if (i < EPM) {
        atomicAdd(&Wp[(size_t)dstA[i] * NG + srcA[i]], wA[i]);
    } else if (i < EPM + EPI) {
        int j = i - EPM;
        atomicAdd(&Wp[(size_t)dstB[j] * NG + NMRNA + srcB[j]], wB[j]);
    }
}

// ---------- acc_pat[b][c] += sum_g Wp[b][g] * h[g][c]  (skinny dense matmul) ----------
#define GCH 128
__global__ __launch_bounds__(256) void k_pat_dense(
        const float* __restrict__ Wp, const float* __restrict__ h,
        float* __restrict__ acc_pat) {
    int c = threadIdx.x;
    int g0 = blockIdx.x * GCH;
    int gend = min(g0 + GCH, NG);
    float acc[BB];
#pragma unroll
    for (int b = 0; b < BB; b++) acc[b] = 0.f;
    for (int g = g0; g < gend; g++) {
        float hv = h[(size_t)g * HID + c];  // coalesced
#pragma unroll
        for (int b = 0; b < BB; b++) acc[b] += Wp[(size_t)b * NG + g] * hv;  // uniform
    }
#pragma unroll
    for (int b = 0; b < BB; b++) atomicAdd(&acc_pat[b * HID + c], acc[b]);
}

// ---------- masked patch pooling (raw sums, no denom); also accumulates masksum ----------
#define PSLICES 32
#define PCHUNK (NP / PSLICES)
__global__ __launch_bounds__(256) void k_pool(
        const float* __restrict__ patches, const float* __restrict__ mask,
        float* __restrict__ pooled, float* __restrict__ masksum) {
    int b = blockIdx.y;
    int p0 = blockIdx.x * PCHUNK;
    int t = threadIdx.x;  // 256 threads x float4 = 1024 = PD
    float4 acc = {0.f, 0.f, 0.f, 0.f};
    float msum = 0.f;
    for (int p = p0; p < p0 + PCHUNK; p++) {
        float m = mask[b * NP + p];  // uniform -> s_load
        msum += m;
        float4 v = ((const float4*)(patches + ((size_t)b * NP + p) * PD))[t];
        acc.x += m * v.x; acc.y += m * v.y; acc.z += m * v.z; acc.w += m * v.w;
    }
    float* op = pooled + (size_t)b * PD + t * 4;
    atomicAdd(op + 0, acc.x);
    atomicAdd(op + 1, acc.y);
    atomicAdd(op + 2, acc.z);
    atomicAdd(op + 3, acc.w);
    if (t == 0) atomicAdd(&masksum[b], msum);
}

// ================= head chain, column-parallel =================
// Stage A: per output col c (grid=HID): pg[b][c] = gelu(acc_pat[b]·proj_w[c] + proj_b[c])
//          wt[b][c] = gelu(lin1/denom)   -- wsi first gelu
// Block = 256 threads = (b = t&15, kk = t>>4), K split 16 ways over kk.
__global__ __launch_bounds__(256) void k_head_a(
        const float* __restrict__ acc_pat, const float* __restrict__ pooled,
        const float* __restrict__ masksum,
        const float* __restrict__ proj_w, const float* __restrict__ proj_b,
        const float* __restrict__ wsi_w, const float* __restrict__ wsi_b,
        float* __restrict__ pg, float* __restrict__ wt) {
    __shared__ float red[256];
    int c = blockIdx.x;
    int t = threadIdx.x;
    int b = t & 15, kk = t >> 4;

    // proj: K = HID, 16 elems/thread
    const float* wr = proj_w + (size_t)c * HID + kk * 16;
    const float* xr = acc_pat + (size_t)b * HID + kk * 16;
    float s = 0.f;
#pragma unroll
    for (int i = 0; i < 16; i += 4) {
        float4 w4 = *(const float4*)(wr + i);
        float4 x4 = *(const float4*)(xr + i);
        s += x4.x * w4.x + x4.y * w4.y + x4.z * w4.z + x4.w * w4.w;
    }
    float tot = kred(s, red, b, kk);
    if (kk == 0) pg[(size_t)b * HID + c] = gelu_exact(tot + proj_b[c]);

    // wsi lin1: K = PD, 64 elems/thread
    const float* wr2 = wsi_w + (size_t)c * PD + kk * 64;
    const float* xr2 = pooled + (size_t)b * PD + kk * 64;
    float s2 = 0.f;
#pragma unroll
    for (int i = 0; i < 64; i += 4) {
        float4 w4 = *(const float4*)(wr2 + i);
        float4 x4 = *(const float4*)(xr2 + i);
        s2 += x4.x * w4.x + x4.y * w4.y + x4.z * w4.z + x4.w * w4.w;
    }
    float tot2 = kred(s2, red, b, kk);
    if (kk == 0) {
        float sm = masksum[b];
        float denom = fmaxf(sm, 1.0f);
        wt[(size_t)b * HID + c] = gelu_exact(tot2 / denom + wsi_b[c] * (sm / denom));
    }
}

// Stage B: ml[b][c] = gelu(wt[b]·mlp_w[c] + mlp_b[c])
__global__ __launch_bounds__(256) void k_head_b(
        const float* __restrict__ wt,
        const float* __restrict__ mlp_w, const float* __restrict__ mlp_b,
        float* __restrict__ ml) {
    __shared__ float red[256];
    int c = blockIdx.x;
    int t = threadIdx.x;
    int b = t & 15, kk = t >> 4;
    const float* wr = mlp_w + (size_t)c * HID + kk * 16;
    const float* xr = wt + (size_t)b * HID + kk * 16;
    float s = 0.f;
#pragma unroll
    for (int i = 0; i < 16; i += 4) {
        float4 w4 = *(const float4*)(wr + i);
        float4 x4 = *(const float4*)(xr + i);
        s += x4.x * w4.x + x4.y * w4.y + x4.z * w4.z + x4.w * w4.w;
    }
    float tot = kred(s, red, b, kk);
    if (kk == 0) ml[(size_t)b * HID + c] = gelu_exact(tot + mlp_b[c]);
}

// Stage C (grid=BB): LN(pg)->vec[0:256); omics logits; LN(ml)->vec[256:512)
__global__ __launch_bounds__(256) void k_head_c(
        const float* __restrict__ pg, const float* __restrict__ ml,
        const float* __restrict__ ln_g, const float* __restrict__ ln_b,
        const float* __restrict__ wln_g, const float* __restrict__ wln_b,
        const float* __restrict__ omics_w, const float* __restrict__ omics_b,
        float* __restrict__ vecbuf, float* __restrict__ out_omics) {
    __shared__ float red[256];
    int b = blockIdx.x, c = threadIdx.x;
    float g = pg[(size_t)b * HID + c];
    float mean = block_reduce_sum(g, red) * (1.0f / HID);
    float d = g - mean;
    float var = block_reduce_sum(d * d, red) * (1.0f / HID);
    float patv = d * rsqrtf(var + 1e-5f) * ln_g[c] + ln_b[c];
    vecbuf[(size_t)b * (2 * HID) + c] = patv;
    for (int o = 0; o < NBINS; o++) {
        float r = block_reduce_sum(patv * omics_w[o * HID + c], red);
        if (c == 0) out_omics[b * NBINS + o] = r + omics_b[o];
    }
    float m = ml[(size_t)b * HID + c];
    mean = block_reduce_sum(m, red) * (1.0f / HID);
    d = m - mean;
    var = block_reduce_sum(d * d, red) * (1.0f / HID);
    vecbuf[(size_t)b * (2 * HID) + HID + c] = d * rsqrtf(var + 1e-5f) * wln_g[c] + wln_b[c];
}

// Stage D: f1[b][c] = gelu(vec[b]·fuse_w1[c] + fuse_b1[c]), K = 2*HID
__global__ __launch_bounds__(256) void k_head_d(
        const float* __restrict__ vecbuf,
        const float* __restrict__ fuse_w1, const float* __restrict__ fuse_b1,
        float* __restrict__ f1) {
    __shared__ float red[256];
    int c = blockIdx.x;
    int t = threadIdx.x;
    int b = t & 15, kk = t >> 4;
    const float* wr = fuse_w1 + (size_t)c * (2 * HID) + kk * 32;
    const float* xr = vecbuf + (size_t)b * (2 * HID) + kk * 32;
    float s = 0.f;
#pragma unroll
    for (int i = 0; i < 32; i += 4) {
        float4 w4 = *(const float4*)(wr + i);
        float4 x4 = *(const float4*)(xr + i);
        s += x4.x * w4.x + x4.y * w4.y + x4.z * w4.z + x4.w * w4.w;
    }
    float tot = kred(s, red, b, kk);
    if (kk == 0) f1[(size_t)b * HID + c] = gelu_exact(tot + fuse_b1[c]);
}

// Stage E (grid=BB): out_fused = f1 @ fuse_w2^T + b2
__global__ __launch_bounds__(256) void k_head_e(
        const float* __restrict__ f1,
        const float* __restrict__ fuse_w2, const float* __restrict__ fuse_b2,
        float* __restrict__ out_fused) {
    __shared__ float red[256];
    int b = blockIdx.x, c = threadIdx.x;
    float h1 = f1[(size_t)b * HID + c];
    for (int o = 0; o < NBINS; o++) {
        float r = block_reduce_sum(h1 * fuse_w2[o * HID + c], red);
        if (c == 0) out_fused[b * NBINS + o] = r + fuse_b2[o];
    }
}

extern "C" void kernel_launch(void* const* d_in, const int* in_sizes, int n_in,
                              void* d_out, int out_size, void* d_ws, size_t ws_size,
                              hipStream_t stream) {
    const float* emb_mirna  = (const float*)d_in[0];
    const float* emb_mrna   = (const float*)d_in[1];
    const float* w_mir2mrna = (const float*)d_in[2];
    const float* w_mrna2mir = (const float*)d_in[3];
    const float* w_mrna2pat = (const float*)d_in[4];
    const float* w_mir2pat  = (const float*)d_in[5];
    const float* reg_w_mrna = (const float*)d_in[6];
    const float* reg_b_mrna = (const float*)d_in[7];
    const float* reg_w_mirna= (const float*)d_in[8];
    const float* reg_b_mirna= (const float*)d_in[9];
    const float* proj_w     = (const float*)d_in[10];
    const float* proj_b     = (const float*)d_in[11];
    const float* ln_g       = (const float*)d_in[12];
    const float* ln_b       = (const float*)d_in[13];
    const float* omics_w    = (const float*)d_in[14];
    const float* omics_b    = (const float*)d_in[15];
    const float* wsi_w      = (const float*)d_in[16];
    const float* wsi_b      = (const float*)d_in[17];
    const float* mlp_w      = (const float*)d_in[18];
    const float* mlp_b      = (const float*)d_in[19];
    const float* wln_g      = (const float*)d_in[20];
    const float* wln_b      = (const float*)d_in[21];
    const float* fuse_w1    = (const float*)d_in[22];
    const float* fuse_b1    = (const float*)d_in[23];
    const float* fuse_w2    = (const float*)d_in[24];
    const float* fuse_b2    = (const float*)d_in[25];
    const float* patches    = (const float*)d_in[26];
    const float* mask       = (const float*)d_in[27];
    const int* src_m2M = (const int*)d_in[28];
    const int* dst_m2M = (const int*)d_in[29];
    const int* src_M2m = (const int*)d_in[30];
    const int* dst_M2m = (const int*)d_in[31];
    const int* src_M2p = (const int*)d_in[32];
    const int* dst_M2p = (const int*)d_in[33];
    const int* src_m2p = (const int*)d_in[34];
    const int* dst_m2p = (const int*)d_in[35];

    float* ws = (float*)d_ws;
    // ---- zeroed region ----
    size_t off = 0;
    float* acc_pat  = ws + off; off += (size_t)BB * HID;       // 4096
    float* pooled   = ws + off; off += (size_t)BB * PD;        // 16384
    float* Wp       = ws + off; off += (size_t)BB * NG;        // [16][22000]
    int* cnt        = (int*)(ws + off); off += NG;             // [22000]
    float* masksum  = ws + off; off += BB;                     // [16]
    size_t zero_floats = off;
    // ---- non-zeroed region (16B-aligned: zero_floats % 4 == 0) ----
    unsigned short* agg_bf = (unsigned short*)(ws + off); off += (size_t)NG * HID / 2;
    unsigned short* wb     = (unsigned short*)(ws + off); off += (size_t)2 * HID * HID / 2;
    float* h        = ws + off; off += (size_t)NG * HID;       // [22000][256]
    float* pg       = ws + off; off += (size_t)BB * HID;
    float* wt       = ws + off; off += (size_t)BB * HID;
    float* ml       = ws + off; off += (size_t)BB * HID;
    float* vecbuf   = ws + off; off += (size_t)BB * 2 * HID;
    float* f1       = ws + off; off += (size_t)BB * HID;
    int* rowptr_A   = (int*)(ws + off); off += NMRNA + 1;
    int* cursor_A   = (int*)(ws + off); off += NMRNA;
    int* rowptr_B   = (int*)(ws + off); off += NMIR + 1;
    int* cursor_B   = (int*)(ws + off); off += NMIR;
    int* srcp_A     = (int*)(ws + off); off += EREG;
    float* wp_A     = ws + off; off += EREG;
    int* srcp_B     = (int*)(ws + off); off += EREG;
    float* wp_B     = ws + off; off += EREG;

    float* out_fused = (float*)d_out;               // [16,4]
    float* out_omics = (float*)d_out + BB * NBINS;  // [16,4]

    hipMemsetAsync(d_ws, 0, zero_floats * sizeof(float), stream);

    // 1. both reg weights -> bf16 (no transpose: [out][in] == MFMA B-fragment layout)
    k_f2b_w<<<(2 * HID * HID + 255) / 256, 256, 0, stream>>>(reg_w_mrna, reg_w_mirna, wb);

    // 2-4. CSR build, both etypes
    k_hist2<<<(2 * EREG + 255) / 256, 256, 0, stream>>>(dst_m2M, dst_M2m, cnt);
    k_scan2<<<2, 1024, 0, stream>>>(cnt, rowptr_A, cursor_A, rowptr_B, cursor_B);
    k_place2<<<(2 * EREG + 255) / 256, 256, 0, stream>>>(
        src_m2M, dst_m2M, w_mir2mrna, cursor_A, srcp_A, wp_A,
        src_M2m, dst_M2m, w_mrna2mir, cursor_B, srcp_B, wp_B);

    // 5. CSR gather (no atomics, no eidx indirection), bf16 agg out
    k_gather2<<<NG, 256, 0, stream>>>(emb_mirna, emb_mrna,
                                      rowptr_A, srcp_A, wp_A,
                                      rowptr_B, srcp_B, wp_B, agg_bf);

    // 6. MFMA node update, both etypes
    k_update2<<<NG / 16, 256, 0, stream>>>(agg_bf, emb_mrna, emb_mirna, wb,
                                           reg_b_mrna, reg_b_mirna, h);

    // 7-8. patient readout: dense weights + skinny matmul
    k_wscatter2<<<(EPM + EPI + 255) / 256, 256, 0, stream>>>(
        src_M2p, dst_M2p, w_mrna2pat, src_m2p, dst_m2p, w_mir2pat, Wp);
    k_pat_dense<<<(NG + GCH - 1) / GCH, 256, 0, stream>>>(Wp, h, acc_pat);

    // 9. wsi masked pooling (+ masksum)
    k_pool<<<dim3(PSLICES, BB), 256, 0, stream>>>(patches, mask, pooled, masksum);

    // 10. head chain, column-parallel (weights spread over 256 blocks, not 16)
    k_head_a<<<HID, 256, 0, stream>>>(acc_pat, pooled, masksum,
                                      proj_w, proj_b, wsi_w, wsi_b, pg, wt);
    k_head_b<<<HID, 256, 0, stream>>>(wt, mlp_w, mlp_b, ml);
    k_head_c<<<BB, 256, 0, stream>>>(pg, ml, ln_g, ln_b, wln_g, wln_b,
                                     omics_w, omics_b, vecbuf, out_omics);
    k_head_d<<<HID, 256, 0, stream>>>(vecbuf, fuse_w1, fuse_b1, f1);
    k_head_e<<<BB, 256, 0, stream>>>(f1, fuse_w2, fuse_b2, out_fused);
}

// Round 3
// 597.020 us; speedup vs baseline: 1.0924x; 1.0034x over previous
//
#include <hip/hip_runtime.h>
#include <math.h>

#define HID 256
#define NBINS 4
#define NMIR 2000
#define NMRNA 20000
#define NG (NMRNA + NMIR)   // 22000 union gene space
#define BB 16
#define NP 2048
#define PD 1024
#define EREG 300000
#define EPM 320000
#define EPI 32000

typedef __attribute__((ext_vector_type(8))) short bf16x8;
typedef __attribute__((ext_vector_type(4))) float f32x4;

__device__ __forceinline__ float gelu_exact(float x) {
    return 0.5f * x * (1.0f + erff(x * 0.7071067811865475f));
}

// fp32 -> bf16 round-to-nearest-even (bits)
__device__ __forceinline__ unsigned short f2b(float f) {
    union { float f; unsigned int u; } v; v.f = f;
    unsigned int u = v.u + 0x7fffu + ((v.u >> 16) & 1u);
    return (unsigned short)(u >> 16);
}

__device__ __forceinline__ float b2f(unsigned short u) {
    union { unsigned int i; float f; } v; v.i = ((unsigned int)u) << 16;
    return v.f;
}

// blockDim.x == 256 assumed
__device__ __forceinline__ float block_reduce_sum(float v, float* red) {
    int c = threadIdx.x;
    red[c] = v;
    __syncthreads();
    for (int st = 128; st > 0; st >>= 1) {
        if (c < st) red[c] += red[c + st];
        __syncthreads();
    }
    float r = red[0];
    __syncthreads();
    return r;
}

// 256-thread block laid out as (b = t&15, kk = t>>4); reduce over kk, result to all
__device__ __forceinline__ float kred(float v, float* red, int b, int kk) {
    red[kk * 16 + b] = v;
    __syncthreads();
    for (int st = 8; st >= 1; st >>= 1) {
        if (kk < st) red[kk * 16 + b] += red[(kk + st) * 16 + b];
        __syncthreads();
    }
    float r = red[b];
    __syncthreads();
    return r;
}

// ================= fused independent prelude =================
// Sections (block ranges): pool | emb->bf16 | hist | wscatter | f2b weights
#define MISC_POOL 512                       // PSLICES(32) * BB(16)
#define PSLICES 32
#define PCHUNK (NP / PSLICES)
#define MISC_EMB (((NMIR + NMRNA) * HID) / 1024)   // 5500, 4 elems/thread
#define MISC_HIST ((2 * EREG + 255) / 256)         // 2344
#define MISC_WSC ((EPM + EPI + 255) / 256)         // 1375
#define MISC_F2B ((2 * HID * HID) / 1024)          // 128
#define MISC_TOTAL (MISC_POOL + MISC_EMB + MISC_HIST + MISC_WSC + MISC_F2B)

__global__ __launch_bounds__(256) void k_misc(
        const float* __restrict__ patches, const float* __restrict__ mask,
        float* __restrict__ pooled, float* __restrict__ masksum,
        const float* __restrict__ emb_mirna, const float* __restrict__ emb_mrna,
        unsigned short* __restrict__ embB_mir, unsigned short* __restrict__ embB_mrna,
        const int* __restrict__ dA, const int* __restrict__ dB, int* __restrict__ cnt,
        const int* __restrict__ srcP, const int* __restrict__ dstP, const float* __restrict__ wP,
        const int* __restrict__ srcI, const int* __restrict__ dstI, const float* __restrict__ wI,
        float* __restrict__ Wp,
        const float* __restrict__ regwA, const float* __restrict__ regwB,
        unsigned short* __restrict__ wb) {
    int bid = blockIdx.x;
    int t = threadIdx.x;
    if (bid < MISC_POOL) {
        // ---- masked patch pooling (raw sums) + masksum ----
        int slice = bid & 31, b = bid >> 5;
        int p0 = slice * PCHUNK;
        float4 acc = {0.f, 0.f, 0.f, 0.f};
        float msum = 0.f;
        for (int p = p0; p < p0 + PCHUNK; p++) {
            float m = mask[b * NP + p];
            msum += m;
            float4 v = ((const float4*)(patches + ((size_t)b * NP + p) * PD))[t];
            acc.x += m * v.x; acc.y += m * v.y; acc.z += m * v.z; acc.w += m * v.w;
        }
        float* op = pooled + (size_t)b * PD + t * 4;
        atomicAdd(op + 0, acc.x);
        atomicAdd(op + 1, acc.y);
        atomicAdd(op + 2, acc.z);
        atomicAdd(op + 3, acc.w);
        if (t == 0) atomicAdd(&masksum[b], msum);
        return;
    }
    bid -= MISC_POOL;
    if (bid < MISC_EMB) {
        // ---- embeddings -> bf16 (4 elems/thread) ----
        size_t e = (size_t)bid * 1024 + t * 4;
        const size_t NM = (size_t)NMIR * HID;  // 512000
        float4 v;
        unsigned short* o;
        if (e < NM) { v = *(const float4*)(emb_mirna + e); o = embB_mir + e; }
        else        { v = *(const float4*)(emb_mrna + (e - NM)); o = embB_mrna + (e - NM); }
        ushort4 u = { f2b(v.x), f2b(v.y), f2b(v.z), f2b(v.w) };
        *(ushort4*)o = u;
        return;
    }
    bid -= MISC_EMB;
    if (bid < MISC_HIST) {
        // ---- CSR histogram, both etypes ----
        int i = bid * 256 + t;
        if (i < EREG) atomicAdd(&cnt[dA[i]], 1);
        else if (i < 2 * EREG) atomicAdd(&cnt[NMRNA + dB[i - EREG]], 1);
        return;
    }
    bid -= MISC_HIST;
    if (bid < MISC_WSC) {
        // ---- pat readout weights Wp[b][g] += w ----
        int i = bid * 256 + t;
        if (i < EPM) {
            atomicAdd(&Wp[(size_t)dstP[i] * NG + srcP[i]], wP[i]);
        } else if (i < EPM + EPI) {
            int j = i - EPM;
            atomicAdd(&Wp[(size_t)dstI[j] * NG + NMRNA + srcI[j]], wI[j]);
        }
        return;
    }
    bid -= MISC_WSC;
    {
        // ---- both reg weights fp32 -> bf16 (4 elems/thread) ----
        size_t e = (size_t)bid * 1024 + t * 4;
        float4 v;
        if (e < (size_t)HID * HID) v = *(const float4*)(regwA + e);
        else v = *(const float4*)(regwB + (e - HID * HID));
        ushort4 u = { f2b(v.x), f2b(v.y), f2b(v.z), f2b(v.w) };
        *(ushort4*)(wb + e) = u;
    }
}

// ---------- exclusive scan: block 0 -> mrna CSR, block 1 -> mir CSR ----------
__global__ __launch_bounds__(1024) void k_scan2(const int* __restrict__ cnt,
                                                int* __restrict__ rpA, int* __restrict__ cuA,
                                                int* __restrict__ rpB, int* __restrict__ cuB) {
    __shared__ int part[1024];
    const int* c = (blockIdx.x == 0) ? cnt : cnt + NMRNA;
    int n = (blockIdx.x == 0) ? NMRNA : NMIR;
    int* rowptr = (blockIdx.x == 0) ? rpA : rpB;
    int* cursor = (blockIdx.x == 0) ? cuA : cuB;
    int t = threadIdx.x;
    int chunk = (n + 1023) >> 10;
    int beg = t * chunk;
    int end = min(beg + chunk, n);
    int s = 0;
    for (int i = beg; i < end; i++) s += c[i];
    part[t] = s;
    __syncthreads();
    for (int st = 1; st < 1024; st <<= 1) {
        int v = (t >= st) ? part[t - st] : 0;
        __syncthreads();
        part[t] += v;
        __syncthreads();
    }
    int off = part[t] - s;  // exclusive prefix
    for (int i = beg; i < end; i++) {
        rowptr[i] = off;
        cursor[i] = off;
        off += c[i];
    }
    if (end == n) rowptr[n] = off;
}

// ---------- placement: permute (src, w) into CSR order ----------
__global__ void k_place2(
        const int* __restrict__ srcA, const int* __restrict__ dstA, const float* __restrict__ wA,
        int* __restrict__ cuA, int* __restrict__ srcpA, float* __restrict__ wpA,
        const int* __restrict__ srcB, const int* __restrict__ dstB, const float* __restrict__ wB,
        int* __restrict__ cuB, int* __restrict__ srcpB, float* __restrict__ wpB) {
    int i = blockIdx.x * blockDim.x + threadIdx.x;
    if (i < EREG) {
        int p = atomicAdd(&cuA[dstA[i]], 1);
        srcpA[p] = srcA[i];
        wpA[p] = wA[i];
    } else if (i < 2 * EREG) {
        int j = i - EREG;
        int p = atomicAdd(&cuB[dstB[j]], 1);
        srcpB[p] = srcB[j];
        wpB[p] = wB[j];
    }
}

// ---------- CSR gather from bf16 emb: one block per dst node; bf16 out [NG][256] ----------
// Per edge, lane l loads ushort4 covering cols 4l..4l+3 (one 8B load = full 512B row/wave).
__global__ __launch_bounds__(256) void k_gather2(
        const unsigned short* __restrict__ embB_mir, const unsigned short* __restrict__ embB_mrna,
        const int* __restrict__ rpA, const int* __restrict__ srcpA, const float* __restrict__ wpA,
        const int* __restrict__ rpB, const int* __restrict__ srcpB, const float* __restrict__ wpB,
        unsigned short* __restrict__ agg) {
    __shared__ float lacc[4][HID];
    int n = blockIdx.x;
    const unsigned short* emb;
    const int* rp; const int* srcp; const float* wp;
    int node;
    if (n < NMRNA) { emb = embB_mir;  rp = rpA; srcp = srcpA; wp = wpA; node = n; }
    else           { emb = embB_mrna; rp = rpB; srcp = srcpB; wp = wpB; node = n - NMRNA; }
    int wv = threadIdx.x >> 6, l = threadIdx.x & 63;
    int beg = rp[node], end = rp[node + 1];
    float a0 = 0.f, a1 = 0.f, a2 = 0.f, a3 = 0.f;
    for (int j = beg + wv; j < end; j += 4) {
        int s = srcp[j];          // wave-uniform -> s_load
        float we = wp[j];
        ushort4 v = *(const ushort4*)(emb + (size_t)s * HID + l * 4);
        a0 += we * b2f(v.x);
        a1 += we * b2f(v.y);
        a2 += we * b2f(v.z);
        a3 += we * b2f(v.w);
    }
    float4 st = { a0, a1, a2, a3 };
    ((float4*)lacc[wv])[l] = st;   // lacc[wv][4l..4l+3]
    __syncthreads();
    int c = threadIdx.x;
    agg[(size_t)n * HID + c] = f2b(lacc[0][c] + lacc[1][c] + lacc[2][c] + lacc[3][c]);
}

// ---------- MFMA node update + fused patient readout ----------
// h_tile = emb + gelu(A @ W^T + bias) kept in LDS (never written to global);
// then acc_pat[b][c] += sum_{16 rows} Wp[b][row]*h_tile[row][c] via atomics.
__global__ __launch_bounds__(256) void k_update2(
        const unsigned short* __restrict__ A,
        const float* __restrict__ emb_mrna, const float* __restrict__ emb_mirna,
        const unsigned short* __restrict__ wb,
        const float* __restrict__ bias_mrna, const float* __restrict__ bias_mirna,
        const float* __restrict__ Wp, float* __restrict__ acc_pat) {
    __shared__ float ht[16][HID + 1];
    int row0 = blockIdx.x * 16;   // global row (NG space); NMRNA % 16 == 0, never straddles
    const float* emb; const unsigned short* Wb; const float* bias; int base;
    if (row0 < NMRNA) { emb = emb_mrna;  Wb = wb;             bias = bias_mrna;  base = 0; }
    else              { emb = emb_mirna; Wb = wb + HID * HID; bias = bias_mirna; base = NMRNA; }
    int wv = threadIdx.x >> 6;
    int lane = threadIdx.x & 63;
    int m = lane & 15;   // A row offset / D col offset
    int q = lane >> 4;   // quad: k = q*8 + j
    bf16x8 afrag[8];
    const unsigned short* arow = A + (size_t)(row0 + m) * HID + q * 8;
#pragma unroll
    for (int kk = 0; kk < 8; kk++)
        afrag[kk] = *(const bf16x8*)(arow + kk * 32);
    f32x4 acc[4];
#pragma unroll
    for (int t = 0; t < 4; t++) acc[t] = (f32x4){0.f, 0.f, 0.f, 0.f};
    int col_base = wv * 64;
#pragma unroll
    for (int t = 0; t < 4; t++) {
        const unsigned short* brow = Wb + (size_t)(col_base + t * 16 + m) * HID + q * 8;
#pragma unroll
        for (int kk = 0; kk < 8; kk++) {
            bf16x8 bfrag = *(const bf16x8*)(brow + kk * 32);
            acc[t] = __builtin_amdgcn_mfma_f32_16x16x32_bf16(afrag[kk], bfrag, acc[t], 0, 0, 0);
        }
    }
#pragma unroll
    for (int t = 0; t < 4; t++) {
        int col = col_base + t * 16 + m;
        float bv = bias[col];
#pragma unroll
        for (int r = 0; r < 4; r++) {
            int lrow = q * 4 + r;                                // local row 0..15
            size_t idxe = (size_t)(row0 - base + lrow) * HID + col;
            ht[lrow][col] = emb[idxe] + gelu_exact(acc[t][r] + bv);
        }
    }
    __syncthreads();
    // fused skinny matmul: per col c, 16 patients x 16 rows
    int c = threadIdx.x;
    float hv[16];
#pragma unroll
    for (int r = 0; r < 16; r++) hv[r] = ht[r][c];
#pragma unroll
    for (int b = 0; b < BB; b++) {
        const float* wpr = Wp + (size_t)b * NG + row0;  // wave-uniform -> s_load
        float s = 0.f;
#pragma unroll
        for (int r = 0; r < 16; r++) s += wpr[r] * hv[r];
        atomicAdd(&acc_pat[b * HID + c], s);
    }
}

// ================= head chain, column-parallel =================
__global__ __launch_bounds__(256) void k_head_a(
        const float* __restrict__ acc_pat, const float* __restrict__ pooled,
        const float* __restrict__ masksum,
        const float* __restrict__ proj_w, const float* __restrict__ proj_b,
        const float* __restrict__ wsi_w, const float* __restrict__ wsi_b,
        float* __restrict__ pg, float* __restrict__ wt) {
    __shared__ float red[256];
    int c = blockIdx.x;
    int t = threadIdx.x;
    int b = t & 15, kk = t >> 4;

    // proj: K = HID, 16 elems/thread
    const float* wr = proj_w + (size_t)c * HID + kk * 16;
    const float* xr = acc_pat + (size_t)b * HID + kk * 16;
    float s = 0.f;
#pragma unroll
    for (int i = 0; i < 16; i += 4) {
        float4 w4 = *(const float4*)(wr + i);
        float4 x4 = *(const float4*)(xr + i);
        s += x4.x * w4.x + x4.y * w4.y + x4.z * w4.z + x4.w * w4.w;
    }
    float tot = kred(s, red, b, kk);
    if (kk == 0) pg[(size_t)b * HID + c] = gelu_exact(tot + proj_b[c]);

    // wsi lin1: K = PD, 64 elems/thread
    const float* wr2 = wsi_w + (size_t)c * PD + kk * 64;
    const float* xr2 = pooled + (size_t)b * PD + kk * 64;
    float s2 = 0.f;
#pragma unroll
    for (int i = 0; i < 64; i += 4) {
        float4 w4 = *(const float4*)(wr2 + i);
        float4 x4 = *(const float4*)(xr2 + i);
        s2 += x4.x * w4.x + x4.y * w4.y + x4.z * w4.z + x4.w * w4.w;
    }
    float tot2 = kred(s2, red, b, kk);
    if (kk == 0) {
        float sm = masksum[b];
        float denom = fmaxf(sm, 1.0f);
        wt[(size_t)b * HID + c] = gelu_exact(tot2 / denom + wsi_b[c] * (sm / denom));
    }
}

__global__ __launch_bounds__(256) void k_head_b(
        const float* __restrict__ wt,
        const float* __restrict__ mlp_w, const float* __restrict__ mlp_b,
        float* __restrict__ ml) {
    __shared__ float red[256];
    int c = blockIdx.x;
    int t = threadIdx.x;
    int b = t & 15, kk = t >> 4;
    const float* wr = mlp_w + (size_t)c * HID + kk * 16;
    const float* xr = wt + (size_t)b * HID + kk * 16;
    float s = 0.f;
#pragma unroll
    for (int i = 0; i < 16; i += 4) {
        float4 w4 = *(const float4*)(wr + i);
        float4 x4 = *(const float4*)(xr + i);
        s += x4.x * w4.x + x4.y * w4.y + x4.z * w4.z + x4.w * w4.w;
    }
    float tot = kred(s, red, b, kk);
    if (kk == 0) ml[(size_t)b * HID + c] = gelu_exact(tot + mlp_b[c]);
}

// Stage C (grid=BB): LN(pg)->vec[0:256); omics logits; LN(ml)->vec[256:512);
// also initializes out_fused with bias (head_d accumulates atomically onto it)
__global__ __launch_bounds__(256) void k_head_c(
        const float* __restrict__ pg, const float* __restrict__ ml,
        const float* __restrict__ ln_g, const float* __restrict__ ln_b,
        const float* __restrict__ wln_g, const float* __restrict__ wln_b,
        const float* __restrict__ omics_w, const float* __restrict__ omics_b,
        const float* __restrict__ fuse_b2,
        float* __restrict__ vecbuf, float* __restrict__ out_omics,
        float* __restrict__ out_fused) {
    __shared__ float red[256];
    int b = blockIdx.x, c = threadIdx.x;
    if (c < NBINS) out_fused[b * NBINS + c] = fuse_b2[c];
    float g = pg[(size_t)b * HID + c];
    float mean = block_reduce_sum(g, red) * (1.0f / HID);
    float d = g - mean;
    float var = block_reduce_sum(d * d, red) * (1.0f / HID);
    float patv = d * rsqrtf(var + 1e-5f) * ln_g[c] + ln_b[c];
    vecbuf[(size_t)b * (2 * HID) + c] = patv;
    for (int o = 0; o < NBINS; o++) {
        float r = block_reduce_sum(patv * omics_w[o * HID + c], red);
        if (c == 0) out_omics[b * NBINS + o] = r + omics_b[o];
    }
    float m = ml[(size_t)b * HID + c];
    mean = block_reduce_sum(m, red) * (1.0f / HID);
    d = m - mean;
    var = block_reduce_sum(d * d, red) * (1.0f / HID);
    vecbuf[(size_t)b * (2 * HID) + HID + c] = d * rsqrtf(var + 1e-5f) * wln_g[c] + wln_b[c];
}

// Stage D (+E fused): f1 = gelu(vec·fuse_w1^T + b1); out_fused += f1 * fuse_w2^T (atomics)
__global__ __launch_bounds__(256) void k_head_d(
        const float* __restrict__ vecbuf,
        const float* __restrict__ fuse_w1, const float* __restrict__ fuse_b1,
        const float* __restrict__ fuse_w2,
        float* __restrict__ out_fused) {
    __shared__ float red[256];
    int c = blockIdx.x;
    int t = threadIdx.x;
    int b = t & 15, kk = t >> 4;
    const float* wr = fuse_w1 + (size_t)c * (2 * HID) + kk * 32;
    const float* xr = vecbuf + (size_t)b * (2 * HID) + kk * 32;
    float s = 0.f;
#pragma unroll
    for (int i = 0; i < 32; i += 4) {
        float4 w4 = *(const float4*)(wr + i);
        float4 x4 = *(const float4*)(xr + i);
        s += x4.x * w4.x + x4.y * w4.y + x4.z * w4.z + x4.w * w4.w;
    }
    float tot = kred(s, red, b, kk);
    if (kk == 0) {
        float h1 = gelu_exact(tot + fuse_b1[c]);
#pragma unroll
        for (int o = 0; o < NBINS; o++)
            atomicAdd(&out_fused[b * NBINS + o], h1 * fuse_w2[o * HID + c]);
    }
}

extern "C" void kernel_launch(void* const* d_in, const int* in_sizes, int n_in,
                              void* d_out, int out_size, void* d_ws, size_t ws_size,
                              hipStream_t stream) {
    const float* emb_mirna  = (const float*)d_in[0];
    const float* emb_mrna   = (const float*)d_in[1];
    const float* w_mir2mrna = (const float*)d_in[2];
    const float* w_mrna2mir = (const float*)d_in[3];
    const float* w_mrna2pat = (const float*)d_in[4];
    const float* w_mir2pat  = (const float*)d_in[5];
    const float* reg_w_mrna = (const float*)d_in[6];
    const float* reg_b_mrna = (const float*)d_in[7];
    const float* reg_w_mirna= (const float*)d_in[8];
    const float* reg_b_mirna= (const float*)d_in[9];
    const float* proj_w     = (const float*)d_in[10];
    const float* proj_b     = (const float*)d_in[11];
    const float* ln_g       = (const float*)d_in[12];
    const float* ln_b       = (const float*)d_in[13];
    const float* omics_w    = (const float*)d_in[14];
    const float* omics_b    = (const float*)d_in[15];
    const float* wsi_w      = (const float*)d_in[16];
    const float* wsi_b      = (const float*)d_in[17];
    const float* mlp_w      = (const float*)d_in[18];
    const float* mlp_b      = (const float*)d_in[19];
    const float* wln_g      = (const float*)d_in[20];
    const float* wln_b      = (const float*)d_in[21];
    const float* fuse_w1    = (const float*)d_in[22];
    const float* fuse_b1    = (const float*)d_in[23];
    const float* fuse_w2    = (const float*)d_in[24];
    const float* fuse_b2    = (const float*)d_in[25];
    const float* patches    = (const float*)d_in[26];
    const float* mask       = (const float*)d_in[27];
    const int* src_m2M = (const int*)d_in[28];
    const int* dst_m2M = (const int*)d_in[29];
    const int* src_M2m = (const int*)d_in[30];
    const int* dst_M2m = (const int*)d_in[31];
    const int* src_M2p = (const int*)d_in[32];
    const int* dst_M2p = (const int*)d_in[33];
    const int* src_m2p = (const int*)d_in[34];
    const int* dst_m2p = (const int*)d_in[35];

    float* ws = (float*)d_ws;
    // ---- zeroed region ----
    size_t off = 0;
    float* acc_pat  = ws + off; off += (size_t)BB * HID;       // 4096
    float* pooled   = ws + off; off += (size_t)BB * PD;        // 16384
    float* Wp       = ws + off; off += (size_t)BB * NG;        // [16][22000]
    int* cnt        = (int*)(ws + off); off += NG;             // [22000]
    float* masksum  = ws + off; off += BB;                     // [16]
    size_t zero_floats = off;
    // ---- non-zeroed region (base 16B-aligned) ----
    unsigned short* agg_bf = (unsigned short*)(ws + off); off += (size_t)NG * HID / 2;
    unsigned short* wb     = (unsigned short*)(ws + off); off += (size_t)2 * HID * HID / 2;
    unsigned short* embB_mir  = (unsigned short*)(ws + off); off += (size_t)NMIR * HID / 2;
    unsigned short* embB_mrna = (unsigned short*)(ws + off); off += (size_t)NMRNA * HID / 2;
    float* pg       = ws + off; off += (size_t)BB * HID;
    float* wt       = ws + off; off += (size_t)BB * HID;
    float* ml       = ws + off; off += (size_t)BB * HID;
    float* vecbuf   = ws + off; off += (size_t)BB * 2 * HID;
    int* rowptr_A   = (int*)(ws + off); off += NMRNA + 1;
    int* cursor_A   = (int*)(ws + off); off += NMRNA;
    int* rowptr_B   = (int*)(ws + off); off += NMIR + 1;
    int* cursor_B   = (int*)(ws + off); off += NMIR;
    int* srcp_A     = (int*)(ws + off); off += EREG;
    float* wp_A     = ws + off; off += EREG;
    int* srcp_B     = (int*)(ws + off); off += EREG;
    float* wp_B     = ws + off; off += EREG;

    float* out_fused = (float*)d_out;               // [16,4]
    float* out_omics = (float*)d_out + BB * NBINS;  // [16,4]

    hipMemsetAsync(d_ws, 0, zero_floats * sizeof(float), stream);

    // 1. fused prelude: pool + emb->bf16 + hist + wscatter + reg-weights->bf16
    k_misc<<<MISC_TOTAL, 256, 0, stream>>>(
        patches, mask, pooled, masksum,
        emb_mirna, emb_mrna, embB_mir, embB_mrna,
        dst_m2M, dst_M2m, cnt,
        src_M2p, dst_M2p, w_mrna2pat, src_m2p, dst_m2p, w_mir2pat, Wp,
        reg_w_mrna, reg_w_mirna, wb);

    // 2-3. CSR build
    k_scan2<<<2, 1024, 0, stream>>>(cnt, rowptr_A, cursor_A, rowptr_B, cursor_B);
    k_place2<<<(2 * EREG + 255) / 256, 256, 0, stream>>>(
        src_m2M, dst_m2M, w_mir2mrna, cursor_A, srcp_A, wp_A,
        src_M2m, dst_M2m, w_mrna2mir, cursor_B, srcp_B, wp_B);

    // 4. CSR gather from bf16 embeddings (half the row traffic, 1 load/edge/lane)
    k_gather2<<<NG, 256, 0, stream>>>(embB_mir, embB_mrna,
                                      rowptr_A, srcp_A, wp_A,
                                      rowptr_B, srcp_B, wp_B, agg_bf);

    // 5. MFMA node update + fused patient readout (h never materialized)
    k_update2<<<NG / 16, 256, 0, stream>>>(agg_bf, emb_mrna, emb_mirna, wb,
                                           reg_b_mrna, reg_b_mirna, Wp, acc_pat);

    // 6-9. head chain, column-parallel
    k_head_a<<<HID, 256, 0, stream>>>(acc_pat, pooled, masksum,
                                      proj_w, proj_b, wsi_w, wsi_b, pg, wt);
    k_head_b<<<HID, 256, 0, stream>>>(wt, mlp_w, mlp_b, ml);
    k_head_c<<<BB, 256, 0, stream>>>(pg, ml, ln_g, ln_b, wln_g, wln_b,
                                     omics_w, omics_b, fuse_b2,
                                     vecbuf, out_omics, out_fused);
    k_head_d<<<HID, 256, 0, stream>>>(vecbuf, fuse_w1, fuse_b1, fuse_w2, out_fused);
}